// Round 4
// baseline (458.494 us; speedup 1.0000x reference)
//
#include <hip/hip_runtime.h>
#include <math.h>

// Problem constants (B=8 batches, N=M=2048 points, D=3)
#define BATCH 8
#define NPTS 2048
#define THREADS 256
#define NTILES 128             // 2048 cols / 16 cols per MFMA tile
#define ROWS_PER_WAVE 16
#define ROWS_PER_BLOCK 64      // 4 waves
#define LOG_M 7.62559580411076 // log(2048)

typedef __attribute__((ext_vector_type(8))) __bf16 bf16x8;
typedef __attribute__((ext_vector_type(4))) float f32x4;

union FragU { unsigned short u[8]; uint4 v; };

__device__ __forceinline__ unsigned short f2bf(float f) {
    union { float f; unsigned u; } x; x.f = f;
    unsigned r = x.u + 0x7FFFu + ((x.u >> 16) & 1u);   // RNE
    return (unsigned short)(r >> 16);
}
__device__ __forceinline__ float bf2f(unsigned short b) {
    union { unsigned u; float f; } x; x.u = ((unsigned)b) << 16;
    return x.f;
}

// Softmin via MFMA. For each row i, col j:
//   eps*args_ij = v_ij + R_i - eps*lnM,  v_ij = x'_i . y'_j + hhe_j,
//   x' = x - 0.5, hhe_j = pot_j - 0.5|y_j|^2 + 0.5*sum(y'_j)
//   res_i = 0.5|x'_i|^2 - 0.375 + eps*lnM - eps*ln2*(m2_i + log2 s_i)
// v is computed by mfma_f32_16x16x32_bf16 with k-slots (2-way bf16 split of
// centered coords: 4 products/dim = 12 slots; 3-way bf16 split of hhe: 3
// slots; slot 15 zero). Quads 2,3 duplicate quads 0,1 (k16-31 = k0-15) so
// acc = 2v; folded into cscale = log2(e)/(2 eps).
// C layout (verified): col=lane&15, row=(lane>>4)*4+reg.
__global__ __launch_bounds__(THREADS) void softmin_pass(
    const float* __restrict__ x, const float* __restrict__ y,
    const float* __restrict__ potSrc, float* __restrict__ potDst,
    float cscale, float k2, float rowc0, int avg)
{
    __shared__ uint4 BF[NTILES][32];  // 64 KB: B fragments, [tile][lane&31]
    __shared__ uint4 AF[4][32];       //  2 KB: A fragments, [wave][lane&31]

    const int type  = blockIdx.z;
    const int batch = blockIdx.y;

    const float* rowP;
    const float* colP;
    int hslot, oslot;
    if (type == 0)      { rowP = x; colP = y; hslot = 1; oslot = 0; }  // f_ba
    else if (type == 1) { rowP = y; colP = x; hslot = 0; oslot = 1; }  // g_ab
    else if (type == 2) { rowP = x; colP = x; hslot = 2; oslot = 2; }  // f_aa
    else                { rowP = y; colP = y; hslot = 3; oslot = 3; }  // g_bb

    rowP += batch * NPTS * 3;
    colP += batch * NPTS * 3;
    const float* hP   = potSrc + (hslot * BATCH + batch) * NPTS;
    const float* oldP = potSrc + (oslot * BATCH + batch) * NPTS;
    float*       outP = potDst + (oslot * BATCH + batch) * NPTS;

    // ---- stage B fragments: per col j, 16 k-slot bf16 values ----
    for (int j = threadIdx.x; j < NPTS; j += THREADS) {
        float y0 = colP[3 * j + 0], y1 = colP[3 * j + 1], y2 = colP[3 * j + 2];
        float pot = hP[j];
        float p0 = y0 - 0.5f, p1 = y1 - 0.5f, p2 = y2 - 0.5f;
        unsigned short h0 = f2bf(p0); unsigned short l0 = f2bf(p0 - bf2f(h0));
        unsigned short h1 = f2bf(p1); unsigned short l1 = f2bf(p1 - bf2f(h1));
        unsigned short h2 = f2bf(p2); unsigned short l2 = f2bf(p2 - bf2f(h2));
        float hhe = pot - 0.5f * (y0 * y0 + y1 * y1 + y2 * y2)
                  + 0.5f * (p0 + p1 + p2);
        unsigned short hA = f2bf(hhe); float r1 = hhe - bf2f(hA);
        unsigned short hB = f2bf(r1);  float r2 = r1 - bf2f(hB);
        unsigned short hC = f2bf(r2);
        FragU f0, f1;
        f0.u[0] = h0; f0.u[1] = l0; f0.u[2] = h0; f0.u[3] = l0;
        f0.u[4] = h1; f0.u[5] = l1; f0.u[6] = h1; f0.u[7] = l1;
        f1.u[0] = h2; f1.u[1] = l2; f1.u[2] = h2; f1.u[3] = l2;
        f1.u[4] = hA; f1.u[5] = hB; f1.u[6] = hC; f1.u[7] = 0;
        BF[j >> 4][j & 15]        = f0.v;   // k0-7 half  (quad 0 lanes)
        BF[j >> 4][16 + (j & 15)] = f1.v;   // k8-15 half (quad 1 lanes)
    }

    // ---- stage A fragments: per row m of each wave's 16 rows ----
    if (threadIdx.x < 128) {
        const int w = threadIdx.x >> 5;
        const int slot = threadIdx.x & 31;
        const int m = slot & 15;
        const int row = blockIdx.x * ROWS_PER_BLOCK + w * ROWS_PER_WAVE + m;
        float x0 = rowP[3 * row + 0], x1 = rowP[3 * row + 1], x2 = rowP[3 * row + 2];
        float p0 = x0 - 0.5f, p1 = x1 - 0.5f, p2 = x2 - 0.5f;
        unsigned short h0 = f2bf(p0); unsigned short l0 = f2bf(p0 - bf2f(h0));
        unsigned short h1 = f2bf(p1); unsigned short l1 = f2bf(p1 - bf2f(h1));
        unsigned short h2 = f2bf(p2); unsigned short l2 = f2bf(p2 - bf2f(h2));
        FragU f;
        if (slot < 16) {  // k0-7
            f.u[0] = h0; f.u[1] = h0; f.u[2] = l0; f.u[3] = l0;
            f.u[4] = h1; f.u[5] = h1; f.u[6] = l1; f.u[7] = l1;
        } else {          // k8-15
            f.u[0] = h2; f.u[1] = h2; f.u[2] = l2; f.u[3] = l2;
            f.u[4] = 0x3F80; f.u[5] = 0x3F80; f.u[6] = 0x3F80; f.u[7] = 0;
        }
        AF[w][slot] = f.v;
    }
    __syncthreads();

    const int lane = threadIdx.x & 63;
    const int wave = threadIdx.x >> 6;
    const int lidx = lane & 31;

    const bf16x8 af = *(const bf16x8*)&AF[wave][lidx];
    const f32x4 zero = {0.0f, 0.0f, 0.0f, 0.0f};

    // ---- pass 1: row maxes of acc over all tiles ----
    float macc[4];
    #pragma unroll
    for (int r = 0; r < 4; ++r) macc[r] = -INFINITY;
    #pragma unroll 4
    for (int t = 0; t < NTILES; ++t) {
        bf16x8 bf = *(const bf16x8*)&BF[t][lidx];
        f32x4 acc = __builtin_amdgcn_mfma_f32_16x16x32_bf16(af, bf, zero, 0, 0, 0);
        #pragma unroll
        for (int r = 0; r < 4; ++r) macc[r] = fmaxf(macc[r], acc[r]);
    }
    // reduce over the 16 cols held by this quad group (xor bits 0..3)
    #pragma unroll
    for (int off = 1; off <= 8; off <<= 1) {
        #pragma unroll
        for (int r = 0; r < 4; ++r)
            macc[r] = fmaxf(macc[r], __shfl_xor(macc[r], off, 64));
    }
    float m2[4], negm2[4];
    #pragma unroll
    for (int r = 0; r < 4; ++r) { m2[r] = macc[r] * cscale; negm2[r] = -m2[r]; }

    // ---- pass 2: s = sum 2^(acc*cscale - m2) ----
    float s[4] = {0.0f, 0.0f, 0.0f, 0.0f};
    #pragma unroll 4
    for (int t = 0; t < NTILES; ++t) {
        bf16x8 bf = *(const bf16x8*)&BF[t][lidx];
        f32x4 acc = __builtin_amdgcn_mfma_f32_16x16x32_bf16(af, bf, zero, 0, 0, 0);
        #pragma unroll
        for (int r = 0; r < 4; ++r)
            s[r] += __builtin_amdgcn_exp2f(__builtin_fmaf(acc[r], cscale, negm2[r]));
    }
    #pragma unroll
    for (int off = 1; off <= 8; off <<= 1) {
        #pragma unroll
        for (int r = 0; r < 4; ++r)
            s[r] += __shfl_xor(s[r], off, 64);
    }

    // ---- epilogue: lanes with col==0 write 4 rows each ----
    if ((lane & 15) == 0) {
        const int quad = lane >> 4;
        #pragma unroll
        for (int r = 0; r < 4; ++r) {
            const int i = blockIdx.x * ROWS_PER_BLOCK + wave * ROWS_PER_WAVE + quad * 4 + r;
            float x0 = rowP[3 * i + 0], x1 = rowP[3 * i + 1], x2 = rowP[3 * i + 2];
            float p0 = x0 - 0.5f, p1 = x1 - 0.5f, p2 = x2 - 0.5f;
            float rowconst = 0.5f * (p0 * p0 + p1 * p1 + p2 * p2) + rowc0;
            float res = rowconst - k2 * (m2[r] + __log2f(s[r]));
            outP[i] = avg ? 0.5f * (oldP[i] + res) : res;
        }
    }
}

// out[b] = (1/N) * sum_i (f_ba - f_aa) + (1/M) * sum_j (g_ab - g_bb)
__global__ void reduce_out(const float* __restrict__ pot, float* __restrict__ out)
{
    const int batch = blockIdx.x;
    const float* fba = pot + (0 * BATCH + batch) * NPTS;
    const float* gab = pot + (1 * BATCH + batch) * NPTS;
    const float* faa = pot + (2 * BATCH + batch) * NPTS;
    const float* gbb = pot + (3 * BATCH + batch) * NPTS;

    float s = 0.0f;
    for (int i = threadIdx.x; i < NPTS; i += blockDim.x)
        s += (fba[i] - faa[i]) + (gab[i] - gbb[i]);

    #pragma unroll
    for (int off = 32; off >= 1; off >>= 1)
        s += __shfl_xor(s, off, 64);

    __shared__ float red[THREADS / 64];
    const int lane = threadIdx.x & 63;
    const int wave = threadIdx.x >> 6;
    if (lane == 0) red[wave] = s;
    __syncthreads();
    if (threadIdx.x == 0) {
        float t = 0.0f;
        for (int w = 0; w < THREADS / 64; ++w) t += red[w];
        out[batch] = t * (1.0f / NPTS);
    }
}

extern "C" void kernel_launch(void* const* d_in, const int* in_sizes, int n_in,
                              void* d_out, int out_size, void* d_ws, size_t ws_size,
                              hipStream_t stream)
{
    const float* x = (const float*)d_in[0];
    const float* y = (const float*)d_in[1];
    float* out = (float*)d_out;

    // Ping-pong potential buffers in workspace: [4 slots][B][NPTS] each.
    const size_t potElems = (size_t)4 * BATCH * NPTS;
    float* P0 = (float*)d_ws;
    float* P1 = P0 + potElems;

    // Zero the initial potentials (h = a_log exactly at init).
    hipMemsetAsync(P0, 0, potElems * sizeof(float), stream);

    // Epsilon schedule: [diam^p] + exp(arange(p ln diam, p ln blur, p ln scale)) + [blur^p]
    double epsl[16];
    int ne = 0;
    epsl[ne++] = 4.0;                       // diameter^2
    const double stop = 2.0 * log(0.05);
    const double step = 2.0 * log(0.5);
    for (double e = 2.0 * log(2.0); e > stop; e += step)
        epsl[ne++] = exp(e);                // 4, 1, 0.25, 0.0625, 0.015625, 0.00390625
    epsl[ne++] = 0.05 * 0.05;               // blur^2 = 0.0025

    float* src = P0;
    float* dst = P1;
    dim3 grid(NPTS / ROWS_PER_BLOCK, BATCH, 4);

    auto launch = [&](double eps, int avg) {
        float cscale = (float)(M_LOG2E / (2.0 * eps));   // acc = 2v -> /2
        float k2     = (float)(eps * M_LN2);
        float rowc0  = (float)(eps * LOG_M - 0.375);
        softmin_pass<<<grid, THREADS, 0, stream>>>(
            x, y, src, dst, cscale, k2, rowc0, avg);
        float* t = src; src = dst; dst = t;
    };

    launch(epsl[0], 0);                       // init (writes direct)
    for (int k = 0; k < ne; ++k)
        launch(epsl[k], 1);                   // damped symmetric Sinkhorn
    launch(epsl[ne - 1], 0);                  // final extrapolation (writes direct)

    reduce_out<<<dim3(BATCH), THREADS, 0, stream>>>(src, out);
}

// Round 5
// 384.099 us; speedup vs baseline: 1.1937x; 1.1937x over previous
//
#include <hip/hip_runtime.h>
#include <math.h>

// Problem constants (B=8 batches, N=M=2048 points, D=3)
#define BATCH 8
#define NPTS 2048
#define THREADS 256
#define NTILES 128             // 2048 cols / 16 cols per MFMA tile
#define FRAGS 2                // A fragments (16 rows each) per wave
#define ROWS_PER_WAVE 32
#define ROWS_PER_BLOCK 128     // 4 waves
#define LOG_M 7.62559580411076 // log(2048)

typedef __attribute__((ext_vector_type(8))) __bf16 bf16x8;
typedef __attribute__((ext_vector_type(4))) float f32x4;

union FragU { unsigned short u[8]; uint4 v; };

__device__ __forceinline__ unsigned short f2bf(float f) {
    union { float f; unsigned u; } x; x.f = f;
    unsigned r = x.u + 0x7FFFu + ((x.u >> 16) & 1u);   // RNE
    return (unsigned short)(r >> 16);
}
__device__ __forceinline__ float bf2f(unsigned short b) {
    union { unsigned u; float f; } x; x.u = ((unsigned)b) << 16;
    return x.f;
}

// Softmin via MFMA, log2-domain args produced directly by the matrix core:
//   arg_ij = (x'_i . y'_j + pot_j - 0.5|y'_j|^2) * log2(e)/eps
// A-frag: 2-way bf16 split of sigma*x' (sigma = log2e/(2eps)) + 1.0 slots;
// B-frag: 2-way split of y' + 3-way split of sigma*hhe. k16-31 dup k0-15
// -> acc = 2*sigma*v = arg directly.  Pass1: macc = max(acc) (1 v_max/entry).
// Pass2: MFMA C-operand initialized to -macc -> acc2 = arg - m2, so only
// exp2 + add per entry.  res = 0.5|x'|^2 + eps*lnM - eps*ln2*(m2 + log2 s).
// 2 A-frags/wave amortize each BF ds_read over 2 MFMAs; 512 blocks = 2/CU
// (8 waves/CU) so MFMA of one wave overlaps VALU of another.
// C layout (verified): col=lane&15, row=(lane>>4)*4+reg.
__global__ __launch_bounds__(THREADS) void softmin_pass(
    const float* __restrict__ x, const float* __restrict__ y,
    const float* __restrict__ potSrc, float* __restrict__ potDst,
    float sigma, float k2, float rowc0, int avg)
{
    __shared__ uint4 BF[NTILES][32];      // 64 KB: B fragments
    __shared__ uint4 AF[4][FRAGS][32];    //  4 KB: A fragments

    const int type  = blockIdx.z;
    const int batch = blockIdx.y;

    const float* rowP;
    const float* colP;
    int hslot, oslot;
    if (type == 0)      { rowP = x; colP = y; hslot = 1; oslot = 0; }  // f_ba
    else if (type == 1) { rowP = y; colP = x; hslot = 0; oslot = 1; }  // g_ab
    else if (type == 2) { rowP = x; colP = x; hslot = 2; oslot = 2; }  // f_aa
    else                { rowP = y; colP = y; hslot = 3; oslot = 3; }  // g_bb

    rowP += batch * NPTS * 3;
    colP += batch * NPTS * 3;
    const float* hP   = potSrc + (hslot * BATCH + batch) * NPTS;
    const float* oldP = potSrc + (oslot * BATCH + batch) * NPTS;
    float*       outP = potDst + (oslot * BATCH + batch) * NPTS;

    // ---- stage B fragments ----
    for (int j = threadIdx.x; j < NPTS; j += THREADS) {
        float y0 = colP[3 * j + 0], y1 = colP[3 * j + 1], y2 = colP[3 * j + 2];
        float p0 = y0 - 0.5f, p1 = y1 - 0.5f, p2 = y2 - 0.5f;
        unsigned short h0 = f2bf(p0); unsigned short l0 = f2bf(p0 - bf2f(h0));
        unsigned short h1 = f2bf(p1); unsigned short l1 = f2bf(p1 - bf2f(h1));
        unsigned short h2 = f2bf(p2); unsigned short l2 = f2bf(p2 - bf2f(h2));
        float hhe = sigma * (hP[j] - 0.5f * (p0 * p0 + p1 * p1 + p2 * p2));
        unsigned short hA = f2bf(hhe); float r1 = hhe - bf2f(hA);
        unsigned short hB = f2bf(r1);  float r2 = r1 - bf2f(hB);
        unsigned short hC = f2bf(r2);
        FragU f0, f1;
        f0.u[0] = h0; f0.u[1] = l0; f0.u[2] = h0; f0.u[3] = l0;
        f0.u[4] = h1; f0.u[5] = l1; f0.u[6] = h1; f0.u[7] = l1;
        f1.u[0] = h2; f1.u[1] = l2; f1.u[2] = h2; f1.u[3] = l2;
        f1.u[4] = hA; f1.u[5] = hB; f1.u[6] = hC; f1.u[7] = 0;
        BF[j >> 4][j & 15]        = f0.v;   // k0-7 half  (quad 0 lanes)
        BF[j >> 4][16 + (j & 15)] = f1.v;   // k8-15 half (quad 1 lanes)
    }

    // ---- stage A fragments: 4 waves x 2 frags x 32 slots = 256 = THREADS ----
    {
        const int t = threadIdx.x;
        const int w = t >> 6, fr = (t >> 5) & 1, idx = t & 31;
        const int row = blockIdx.x * ROWS_PER_BLOCK + w * ROWS_PER_WAVE
                      + fr * 16 + (idx & 15);
        float x0 = rowP[3 * row + 0], x1 = rowP[3 * row + 1], x2 = rowP[3 * row + 2];
        float p0 = sigma * (x0 - 0.5f), p1 = sigma * (x1 - 0.5f), p2 = sigma * (x2 - 0.5f);
        unsigned short h0 = f2bf(p0); unsigned short l0 = f2bf(p0 - bf2f(h0));
        unsigned short h1 = f2bf(p1); unsigned short l1 = f2bf(p1 - bf2f(h1));
        unsigned short h2 = f2bf(p2); unsigned short l2 = f2bf(p2 - bf2f(h2));
        FragU f;
        if (idx < 16) {   // k0-7
            f.u[0] = h0; f.u[1] = h0; f.u[2] = l0; f.u[3] = l0;
            f.u[4] = h1; f.u[5] = h1; f.u[6] = l1; f.u[7] = l1;
        } else {          // k8-15
            f.u[0] = h2; f.u[1] = h2; f.u[2] = l2; f.u[3] = l2;
            f.u[4] = 0x3F80; f.u[5] = 0x3F80; f.u[6] = 0x3F80; f.u[7] = 0;
        }
        AF[w][fr][idx] = f.v;
    }
    __syncthreads();

    const int lane = threadIdx.x & 63;
    const int wave = threadIdx.x >> 6;
    const int lidx = lane & 31;

    const bf16x8 af0 = *(const bf16x8*)&AF[wave][0][lidx];
    const bf16x8 af1 = *(const bf16x8*)&AF[wave][1][lidx];
    const f32x4 zero = {0.0f, 0.0f, 0.0f, 0.0f};

    // ---- pass 1: row maxes of arg ----
    float macc[FRAGS][4];
    #pragma unroll
    for (int f = 0; f < FRAGS; ++f)
        #pragma unroll
        for (int r = 0; r < 4; ++r) macc[f][r] = -INFINITY;

    #pragma unroll 2
    for (int t = 0; t < NTILES; ++t) {
        bf16x8 bf = *(const bf16x8*)&BF[t][lidx];
        f32x4 a0 = __builtin_amdgcn_mfma_f32_16x16x32_bf16(af0, bf, zero, 0, 0, 0);
        f32x4 a1 = __builtin_amdgcn_mfma_f32_16x16x32_bf16(af1, bf, zero, 0, 0, 0);
        #pragma unroll
        for (int r = 0; r < 4; ++r) {
            macc[0][r] = fmaxf(macc[0][r], a0[r]);
            macc[1][r] = fmaxf(macc[1][r], a1[r]);
        }
    }
    #pragma unroll
    for (int off = 1; off <= 8; off <<= 1)
        #pragma unroll
        for (int f = 0; f < FRAGS; ++f)
            #pragma unroll
            for (int r = 0; r < 4; ++r)
                macc[f][r] = fmaxf(macc[f][r], __shfl_xor(macc[f][r], off, 64));

    f32x4 nm0, nm1;
    #pragma unroll
    for (int r = 0; r < 4; ++r) { nm0[r] = -macc[0][r]; nm1[r] = -macc[1][r]; }

    // ---- pass 2: s = sum 2^(arg - m2), subtraction done by MFMA C-init ----
    float s[FRAGS][4] = {{0,0,0,0},{0,0,0,0}};
    #pragma unroll 2
    for (int t = 0; t < NTILES; ++t) {
        bf16x8 bf = *(const bf16x8*)&BF[t][lidx];
        f32x4 a0 = __builtin_amdgcn_mfma_f32_16x16x32_bf16(af0, bf, nm0, 0, 0, 0);
        f32x4 a1 = __builtin_amdgcn_mfma_f32_16x16x32_bf16(af1, bf, nm1, 0, 0, 0);
        #pragma unroll
        for (int r = 0; r < 4; ++r) {
            s[0][r] += __builtin_amdgcn_exp2f(a0[r]);
            s[1][r] += __builtin_amdgcn_exp2f(a1[r]);
        }
    }
    #pragma unroll
    for (int off = 1; off <= 8; off <<= 1)
        #pragma unroll
        for (int f = 0; f < FRAGS; ++f)
            #pragma unroll
            for (int r = 0; r < 4; ++r)
                s[f][r] += __shfl_xor(s[f][r], off, 64);

    // ---- epilogue: lanes with col==0 write 8 rows each ----
    if ((lane & 15) == 0) {
        const int quad = lane >> 4;
        #pragma unroll
        for (int f = 0; f < FRAGS; ++f) {
            #pragma unroll
            for (int r = 0; r < 4; ++r) {
                const int i = blockIdx.x * ROWS_PER_BLOCK + wave * ROWS_PER_WAVE
                            + f * 16 + quad * 4 + r;
                float x0 = rowP[3 * i + 0], x1 = rowP[3 * i + 1], x2 = rowP[3 * i + 2];
                float p0 = x0 - 0.5f, p1 = x1 - 0.5f, p2 = x2 - 0.5f;
                float rowconst = 0.5f * (p0 * p0 + p1 * p1 + p2 * p2) + rowc0;
                float res = rowconst - k2 * (macc[f][r] + __log2f(s[f][r]));
                outP[i] = avg ? 0.5f * (oldP[i] + res) : res;
            }
        }
    }
}

// out[b] = (1/N) * sum_i (f_ba - f_aa) + (1/M) * sum_j (g_ab - g_bb)
__global__ void reduce_out(const float* __restrict__ pot, float* __restrict__ out)
{
    const int batch = blockIdx.x;
    const float* fba = pot + (0 * BATCH + batch) * NPTS;
    const float* gab = pot + (1 * BATCH + batch) * NPTS;
    const float* faa = pot + (2 * BATCH + batch) * NPTS;
    const float* gbb = pot + (3 * BATCH + batch) * NPTS;

    float s = 0.0f;
    for (int i = threadIdx.x; i < NPTS; i += blockDim.x)
        s += (fba[i] - faa[i]) + (gab[i] - gbb[i]);

    #pragma unroll
    for (int off = 32; off >= 1; off >>= 1)
        s += __shfl_xor(s, off, 64);

    __shared__ float red[THREADS / 64];
    const int lane = threadIdx.x & 63;
    const int wave = threadIdx.x >> 6;
    if (lane == 0) red[wave] = s;
    __syncthreads();
    if (threadIdx.x == 0) {
        float t = 0.0f;
        for (int w = 0; w < THREADS / 64; ++w) t += red[w];
        out[batch] = t * (1.0f / NPTS);
    }
}

extern "C" void kernel_launch(void* const* d_in, const int* in_sizes, int n_in,
                              void* d_out, int out_size, void* d_ws, size_t ws_size,
                              hipStream_t stream)
{
    const float* x = (const float*)d_in[0];
    const float* y = (const float*)d_in[1];
    float* out = (float*)d_out;

    // Ping-pong potential buffers in workspace: [4 slots][B][NPTS] each.
    const size_t potElems = (size_t)4 * BATCH * NPTS;
    float* P0 = (float*)d_ws;
    float* P1 = P0 + potElems;

    // Zero the initial potentials (h = a_log exactly at init).
    hipMemsetAsync(P0, 0, potElems * sizeof(float), stream);

    // Epsilon schedule: [diam^p] + exp(arange(p ln diam, p ln blur, p ln scale)) + [blur^p]
    double epsl[16];
    int ne = 0;
    epsl[ne++] = 4.0;                       // diameter^2
    const double stop = 2.0 * log(0.05);
    const double step = 2.0 * log(0.5);
    for (double e = 2.0 * log(2.0); e > stop; e += step)
        epsl[ne++] = exp(e);                // 4, 1, 0.25, 0.0625, 0.015625, 0.00390625
    epsl[ne++] = 0.05 * 0.05;               // blur^2 = 0.0025

    float* src = P0;
    float* dst = P1;
    dim3 grid(NPTS / ROWS_PER_BLOCK, BATCH, 4);

    auto launch = [&](double eps, int avg) {
        float sigma = (float)(M_LOG2E / (2.0 * eps));  // k-dup doubling folded in
        float k2    = (float)(eps * M_LN2);
        float rowc0 = (float)(eps * LOG_M);
        softmin_pass<<<grid, THREADS, 0, stream>>>(
            x, y, src, dst, sigma, k2, rowc0, avg);
        float* t = src; src = dst; dst = t;
    };

    launch(epsl[0], 0);                       // init (writes direct)
    for (int k = 0; k < ne; ++k)
        launch(epsl[k], 1);                   // damped symmetric Sinkhorn
    launch(epsl[ne - 1], 0);                  // final extrapolation (writes direct)

    reduce_out<<<dim3(BATCH), THREADS, 0, stream>>>(src, out);
}

// Round 6
// 278.921 us; speedup vs baseline: 1.6438x; 1.3771x over previous
//
#include <hip/hip_runtime.h>
#include <math.h>

// Problem constants (B=8 batches, N=M=2048 points, D=3)
#define BATCH 8
#define NPTS 2048
#define THREADS 256
#define NTILES 128             // 2048 cols / 16 cols per MFMA tile
#define FRAGS 2                // A fragments (16 rows each) per wave
#define ROWS_PER_WAVE 32
#define ROWS_PER_BLOCK 128     // 4 waves
#define LOG_M 7.62559580411076 // log(2048)

typedef __attribute__((ext_vector_type(8))) __bf16 bf16x8;
typedef __attribute__((ext_vector_type(4))) float f32x4;

union FragU { unsigned short u[8]; uint4 v; };

__device__ __forceinline__ unsigned short f2bf(float f) {
    union { float f; unsigned u; } x; x.f = f;
    unsigned r = x.u + 0x7FFFu + ((x.u >> 16) & 1u);   // RNE
    return (unsigned short)(r >> 16);
}
__device__ __forceinline__ float bf2f(unsigned short b) {
    union { unsigned u; float f; } x; x.u = ((unsigned)b) << 16;
    return x.f;
}

// Single-pass softmin via MFMA with an *estimated* LSE shift (no max pass).
//   arg_ij = (x'_i . y'_j + pot_j - 0.5|y'_j|^2) * log2(e)/eps   (log2 domain)
// MFMA (16x16x32 bf16) produces arg via 2-way bf16 splits of sigma*x' and y'
// plus a 3-way split of sigma*hhe; k16-31 duplicate k0-15 (acc=2*sigma*v,
// sigma = log2e/(2eps)). The LSE shift is m2_hat = (rowconst - old)/k2
// (old = this slot's current potential): exact algebra for ANY shift, and
// with this choice res = old - k2*log2(sum 2^(arg - m2_hat)) -- rowconst
// cancels. Shift estimate is within ~44 log2 units of the true max (worst
// case at 4x eps drops), far inside f32's ~116-unit range limit.
// The -m2_hat enters as the MFMA C operand -> per entry just exp2 + add.
// C layout (verified): col=lane&15, row=(lane>>4)*4+reg.
__global__ __launch_bounds__(THREADS) void softmin_pass(
    const float* __restrict__ x, const float* __restrict__ y,
    const float* __restrict__ potSrc, float* __restrict__ potDst,
    float sigma, float k2, float inv_k2, float rowc0, int avg)
{
    __shared__ uint4 BF[NTILES][32];      // 64 KB: B fragments
    __shared__ uint4 AF[4][FRAGS][32];    //  4 KB: A fragments
    __shared__ float NM[ROWS_PER_BLOCK];  // -m2_hat per row

    const int type  = blockIdx.z;
    const int batch = blockIdx.y;

    const float* rowP;
    const float* colP;
    int hslot, oslot;
    if (type == 0)      { rowP = x; colP = y; hslot = 1; oslot = 0; }  // f_ba
    else if (type == 1) { rowP = y; colP = x; hslot = 0; oslot = 1; }  // g_ab
    else if (type == 2) { rowP = x; colP = x; hslot = 2; oslot = 2; }  // f_aa
    else                { rowP = y; colP = y; hslot = 3; oslot = 3; }  // g_bb

    rowP += batch * NPTS * 3;
    colP += batch * NPTS * 3;
    const float* hP   = potSrc + (hslot * BATCH + batch) * NPTS;
    const float* oldP = potSrc + (oslot * BATCH + batch) * NPTS;
    float*       outP = potDst + (oslot * BATCH + batch) * NPTS;

    // ---- stage B fragments ----
    for (int j = threadIdx.x; j < NPTS; j += THREADS) {
        float y0 = colP[3 * j + 0], y1 = colP[3 * j + 1], y2 = colP[3 * j + 2];
        float p0 = y0 - 0.5f, p1 = y1 - 0.5f, p2 = y2 - 0.5f;
        unsigned short h0 = f2bf(p0); unsigned short l0 = f2bf(p0 - bf2f(h0));
        unsigned short h1 = f2bf(p1); unsigned short l1 = f2bf(p1 - bf2f(h1));
        unsigned short h2 = f2bf(p2); unsigned short l2 = f2bf(p2 - bf2f(h2));
        float hhe = sigma * (hP[j] - 0.5f * (p0 * p0 + p1 * p1 + p2 * p2));
        unsigned short hA = f2bf(hhe); float r1 = hhe - bf2f(hA);
        unsigned short hB = f2bf(r1);  float r2 = r1 - bf2f(hB);
        unsigned short hC = f2bf(r2);
        FragU f0, f1;
        f0.u[0] = h0; f0.u[1] = l0; f0.u[2] = h0; f0.u[3] = l0;
        f0.u[4] = h1; f0.u[5] = l1; f0.u[6] = h1; f0.u[7] = l1;
        f1.u[0] = h2; f1.u[1] = l2; f1.u[2] = h2; f1.u[3] = l2;
        f1.u[4] = hA; f1.u[5] = hB; f1.u[6] = hC; f1.u[7] = 0;
        BF[j >> 4][j & 15]        = f0.v;   // k0-7 half  (quad 0 lanes)
        BF[j >> 4][16 + (j & 15)] = f1.v;   // k8-15 half (quad 1 lanes)
    }

    // ---- stage A fragments: 4 waves x 2 frags x 32 slots = 256 = THREADS ----
    {
        const int t = threadIdx.x;
        const int w = t >> 6, fr = (t >> 5) & 1, idx = t & 31;
        const int row = blockIdx.x * ROWS_PER_BLOCK + w * ROWS_PER_WAVE
                      + fr * 16 + (idx & 15);
        float x0 = rowP[3 * row + 0], x1 = rowP[3 * row + 1], x2 = rowP[3 * row + 2];
        float p0 = sigma * (x0 - 0.5f), p1 = sigma * (x1 - 0.5f), p2 = sigma * (x2 - 0.5f);
        unsigned short h0 = f2bf(p0); unsigned short l0 = f2bf(p0 - bf2f(h0));
        unsigned short h1 = f2bf(p1); unsigned short l1 = f2bf(p1 - bf2f(h1));
        unsigned short h2 = f2bf(p2); unsigned short l2 = f2bf(p2 - bf2f(h2));
        FragU f;
        if (idx < 16) {   // k0-7
            f.u[0] = h0; f.u[1] = h0; f.u[2] = l0; f.u[3] = l0;
            f.u[4] = h1; f.u[5] = h1; f.u[6] = l1; f.u[7] = l1;
        } else {          // k8-15
            f.u[0] = h2; f.u[1] = h2; f.u[2] = l2; f.u[3] = l2;
            f.u[4] = 0x3F80; f.u[5] = 0x3F80; f.u[6] = 0x3F80; f.u[7] = 0;
        }
        AF[w][fr][idx] = f.v;
    }

    // ---- stage per-row shift: NM[r] = (old - rowconst)/k2 = -m2_hat ----
    if (threadIdx.x < ROWS_PER_BLOCK) {
        const int i = blockIdx.x * ROWS_PER_BLOCK + threadIdx.x;
        float x0 = rowP[3 * i + 0], x1 = rowP[3 * i + 1], x2 = rowP[3 * i + 2];
        float p0 = x0 - 0.5f, p1 = x1 - 0.5f, p2 = x2 - 0.5f;
        float rowconst = 0.5f * (p0 * p0 + p1 * p1 + p2 * p2) + rowc0;
        NM[threadIdx.x] = (oldP[i] - rowconst) * inv_k2;
    }
    __syncthreads();

    const int lane = threadIdx.x & 63;
    const int wave = threadIdx.x >> 6;
    const int lidx = lane & 31;
    const int quad = lane >> 4;

    const bf16x8 af0 = *(const bf16x8*)&AF[wave][0][lidx];
    const bf16x8 af1 = *(const bf16x8*)&AF[wave][1][lidx];
    const f32x4 nm0 = *(const f32x4*)&NM[wave * ROWS_PER_WAVE + quad * 4];
    const f32x4 nm1 = *(const f32x4*)&NM[wave * ROWS_PER_WAVE + 16 + quad * 4];

    // ---- single pass: s = sum 2^(arg - m2_hat); shift via MFMA C-init ----
    float s[FRAGS][4] = {{0,0,0,0},{0,0,0,0}};
    #pragma unroll 4
    for (int t = 0; t < NTILES; ++t) {
        bf16x8 bf = *(const bf16x8*)&BF[t][lidx];
        f32x4 a0 = __builtin_amdgcn_mfma_f32_16x16x32_bf16(af0, bf, nm0, 0, 0, 0);
        f32x4 a1 = __builtin_amdgcn_mfma_f32_16x16x32_bf16(af1, bf, nm1, 0, 0, 0);
        #pragma unroll
        for (int r = 0; r < 4; ++r) {
            s[0][r] += __builtin_amdgcn_exp2f(a0[r]);
            s[1][r] += __builtin_amdgcn_exp2f(a1[r]);
        }
    }
    #pragma unroll
    for (int off = 1; off <= 8; off <<= 1)
        #pragma unroll
        for (int f = 0; f < FRAGS; ++f)
            #pragma unroll
            for (int r = 0; r < 4; ++r)
                s[f][r] += __shfl_xor(s[f][r], off, 64);

    // ---- epilogue: res = old - k2*log2(s); col==0 lanes write 8 rows ----
    if ((lane & 15) == 0) {
        #pragma unroll
        for (int f = 0; f < FRAGS; ++f) {
            #pragma unroll
            for (int r = 0; r < 4; ++r) {
                const int i = blockIdx.x * ROWS_PER_BLOCK + wave * ROWS_PER_WAVE
                            + f * 16 + quad * 4 + r;
                float oldv = oldP[i];
                float res = oldv - k2 * __log2f(s[f][r]);
                outP[i] = avg ? 0.5f * (oldv + res) : res;
            }
        }
    }
}

// out[b] = (1/N) * sum_i (f_ba - f_aa) + (1/M) * sum_j (g_ab - g_bb)
__global__ void reduce_out(const float* __restrict__ pot, float* __restrict__ out)
{
    const int batch = blockIdx.x;
    const float* fba = pot + (0 * BATCH + batch) * NPTS;
    const float* gab = pot + (1 * BATCH + batch) * NPTS;
    const float* faa = pot + (2 * BATCH + batch) * NPTS;
    const float* gbb = pot + (3 * BATCH + batch) * NPTS;

    float s = 0.0f;
    for (int i = threadIdx.x; i < NPTS; i += blockDim.x)
        s += (fba[i] - faa[i]) + (gab[i] - gbb[i]);

    #pragma unroll
    for (int off = 32; off >= 1; off >>= 1)
        s += __shfl_xor(s, off, 64);

    __shared__ float red[THREADS / 64];
    const int lane = threadIdx.x & 63;
    const int wave = threadIdx.x >> 6;
    if (lane == 0) red[wave] = s;
    __syncthreads();
    if (threadIdx.x == 0) {
        float t = 0.0f;
        for (int w = 0; w < THREADS / 64; ++w) t += red[w];
        out[batch] = t * (1.0f / NPTS);
    }
}

extern "C" void kernel_launch(void* const* d_in, const int* in_sizes, int n_in,
                              void* d_out, int out_size, void* d_ws, size_t ws_size,
                              hipStream_t stream)
{
    const float* x = (const float*)d_in[0];
    const float* y = (const float*)d_in[1];
    float* out = (float*)d_out;

    // Ping-pong potential buffers in workspace: [4 slots][B][NPTS] each.
    const size_t potElems = (size_t)4 * BATCH * NPTS;
    float* P0 = (float*)d_ws;
    float* P1 = P0 + potElems;

    // Zero the initial potentials (h = a_log exactly at init; old = 0).
    hipMemsetAsync(P0, 0, potElems * sizeof(float), stream);

    // Epsilon schedule: [diam^p] + exp(arange(p ln diam, p ln blur, p ln scale)) + [blur^p]
    double epsl[16];
    int ne = 0;
    epsl[ne++] = 4.0;                       // diameter^2
    const double stop = 2.0 * log(0.05);
    const double step = 2.0 * log(0.5);
    for (double e = 2.0 * log(2.0); e > stop; e += step)
        epsl[ne++] = exp(e);                // 4, 1, 0.25, 0.0625, 0.015625, 0.00390625
    epsl[ne++] = 0.05 * 0.05;               // blur^2 = 0.0025

    float* src = P0;
    float* dst = P1;
    dim3 grid(NPTS / ROWS_PER_BLOCK, BATCH, 4);

    auto launch = [&](double eps, int avg) {
        float sigma  = (float)(M_LOG2E / (2.0 * eps));  // k-dup doubling folded in
        float k2     = (float)(eps * M_LN2);
        float inv_k2 = (float)(1.0 / (eps * M_LN2));
        float rowc0  = (float)(eps * LOG_M);
        softmin_pass<<<grid, THREADS, 0, stream>>>(
            x, y, src, dst, sigma, k2, inv_k2, rowc0, avg);
        float* t = src; src = dst; dst = t;
    };

    launch(epsl[0], 0);                       // init (writes direct)
    for (int k = 0; k < ne; ++k)
        launch(epsl[k], 1);                   // damped symmetric Sinkhorn
    launch(epsl[ne - 1], 0);                  // final extrapolation (writes direct)

    reduce_out<<<dim3(BATCH), THREADS, 0, stream>>>(src, out);
}